// Round 14
// baseline (3250.505 us; speedup 1.0000x reference)
//
#include <hip/hip_runtime.h>
#include <stdint.h>
#include <stddef.h>

#define B_    64
#define T_    16
#define DF_   512
#define S_    196
#define DIN_  512
#define H_    8
#define DH_   64
#define DM_   1024
#define MEM_  25
#define HN_   32
#define MR_   (B_*S_)     /* 12544 rows per tick */
#define TC_   2           /* ticks per chunk */
#define NCH_  (T_/TC_)    /* 8 chunks */
#define MCC_  (MR_*TC_)   /* 25088 rows per chunk */

typedef short bf16x8 __attribute__((ext_vector_type(8)));
typedef short short4v __attribute__((ext_vector_type(4)));
typedef float f32x4  __attribute__((ext_vector_type(4)));

__device__ __forceinline__ float b2f(short h){
  unsigned u = ((unsigned)(unsigned short)h) << 16;
  float f; __builtin_memcpy(&f, &u, 4); return f;
}
__device__ __forceinline__ short f2b(float f){
  unsigned u; __builtin_memcpy(&u, &f, 4);
  u = (u + 0x7fffu + ((u >> 16) & 1u)) >> 16;
  return (short)(unsigned short)u;
}
__device__ __forceinline__ float clip015(float d){
  return d < 0.f ? 0.f : (d > 15.f ? 15.f : d);
}

// ---------------------------------------------------------------------------
// bf16 MFMA GEMM body (verified R8..R12 code). 128x128 tile, BK=64, 4 waves
// 2x2 over tid 0..255, 16x16x32 MFMA, global_load_lds width-16, XOR chunk
// swizzle. aload=0 lets a twin block skip A-tile loads (shared lA).
// LNEPI=0: +bias. LNEPI=2: transposed-LN fold (col stats, row gw/bw).
// No spins / unbounded waits anywhere in this file.
// ---------------------------------------------------------------------------
template<int OUTF32, int LNEPI>
__device__ __forceinline__ void gemm_body(int tid, int bx, int by, int aload,
    short* lA, short* lB,
    const short* __restrict__ A, const short* __restrict__ WT,
    void* __restrict__ Cout,
    const float* __restrict__ biasA, const float* __restrict__ biasB, int nsplit,
    const float* __restrict__ mu, const float* __restrict__ iv,
    const float* __restrict__ gw, const float* __restrict__ bw,
    int M, int N, int K, int lda, int ldc)
{
  const int w = tid >> 6, l = tid & 63;
  const int m0 = bx * 128, n0 = by * 128;
  const int wm = (w >> 1) * 64, wn = (w & 1) * 64;
  f32x4 acc[4][4];
  #pragma unroll
  for (int i=0;i<4;i++)
    #pragma unroll
    for (int j=0;j<4;j++) acc[i][j] = (f32x4){0.f,0.f,0.f,0.f};

  for (int k0 = 0; k0 < K; k0 += 64) {
    #pragma unroll
    for (int rnd = 0; rnd < 4; ++rnd) {
      int cb = (rnd*4 + w) * 64;
      int slot = cb + l;
      int row = slot >> 3, kb = slot & 7;
      int kc = k0 + ((kb ^ (row & 7)) << 3);
      if (aload) {
        int gm = m0 + row; if (gm > M-1) gm = M-1;
        __builtin_amdgcn_global_load_lds(
            (const __attribute__((address_space(1))) void*)(A + (size_t)gm * lda + kc),
            (__attribute__((address_space(3))) void*)&lA[cb*8], 16, 0, 0);
      }
      __builtin_amdgcn_global_load_lds(
          (const __attribute__((address_space(1))) void*)(WT + (size_t)(n0 + row) * K + kc),
          (__attribute__((address_space(3))) void*)&lB[cb*8], 16, 0, 0);
    }
    asm volatile("s_waitcnt vmcnt(0)" ::: "memory");
    __syncthreads();
    #pragma unroll
    for (int ks = 0; ks < 2; ++ks) {
      bf16x8 af[4], bfr[4];
      #pragma unroll
      for (int i = 0; i < 4; ++i) {
        int ra = wm + i*16 + (l & 15);
        int c  = ks*4 + (l >> 4);
        af[i]  = *(const bf16x8*)&lA[ra*64 + ((c ^ (ra & 7)) << 3)];
        int rb = wn + i*16 + (l & 15);
        bfr[i] = *(const bf16x8*)&lB[rb*64 + ((c ^ (rb & 7)) << 3)];
      }
      #pragma unroll
      for (int i = 0; i < 4; ++i)
        #pragma unroll
        for (int j = 0; j < 4; ++j)
          acc[i][j] = __builtin_amdgcn_mfma_f32_16x16x32_bf16(af[i], bfr[j], acc[i][j], 0, 0, 0);
    }
    __syncthreads();
  }
  #pragma unroll
  for (int i = 0; i < 4; ++i) {
    #pragma unroll
    for (int j = 0; j < 4; ++j) {
      int gn = n0 + wn + j*16 + (l & 15);
      float ivn = 0.f, mun = 0.f, bb = 0.f;
      if (LNEPI == 2) { ivn = iv[gn]; mun = mu[gn]; }
      else bb = biasA ? ((gn < nsplit) ? biasA[gn] : biasB[gn - nsplit]) : 0.f;
      #pragma unroll
      for (int r = 0; r < 4; ++r) {
        int gm = m0 + wm + i*16 + (l >> 4)*4 + r;
        if (gm < M) {
          float v;
          if (LNEPI == 2) v = ivn*(acc[i][j][r] - mun*gw[gm]) + bw[gm];
          else            v = acc[i][j][r] + bb;
          if (OUTF32) ((float*)Cout)[(size_t)gm * ldc + gn] = v;
          else        ((short*)Cout)[(size_t)gm * ldc + gn] = f2b(v);
        }
      }
    }
  }
}

// Standalone 256-thread GEMM kernel (chunk-0 KVT / fallback).
template<int OUTF32, int LNEPI>
__global__ __launch_bounds__(256,2) void gemm_k(
    const short* __restrict__ A, const short* __restrict__ WT,
    void* __restrict__ Cout,
    const float* __restrict__ biasA, const float* __restrict__ biasB, int nsplit,
    const float* __restrict__ mu, const float* __restrict__ iv,
    const float* __restrict__ gw, const float* __restrict__ bw,
    int M, int N, int K, int lda, int ldc)
{
  __shared__ short lA[128*64];
  __shared__ short lB[128*64];
  gemm_body<OUTF32,LNEPI>(threadIdx.x, blockIdx.x, blockIdx.y, 1, lA, lB,
                          A, WT, Cout, biasA, biasB, nsplit, mu, iv, gw, bw,
                          M, N, K, lda, ldc);
}

// Weight-fold GEMMs + chunk-0 kv GEMM in one launch.
__global__ __launch_bounds__(256,2) void gemm_prep3(
    const short* __restrict__ WqpB, const short* __restrict__ WqT,
    short* __restrict__ WqqB,
    const short* __restrict__ WsynTt, const short* __restrict__ WoB,
    short* __restrict__ WsynF,
    const short* __restrict__ xT, const short* __restrict__ WkvT,
    const float* __restrict__ bkv, short* __restrict__ kvp0)
{
  __shared__ short lA[128*64];
  __shared__ short lB[128*64];
  int blk = blockIdx.x;
  if (blk < 16)
    gemm_body<0,0>(threadIdx.x, blk & 3, blk >> 2, 1, lA, lB, WqpB, WqT, WqqB,
                   nullptr, nullptr, 1<<30, nullptr, nullptr, nullptr, nullptr,
                   512, 512, 512, 512, 512);
  else if (blk < 80) {
    int b2 = blk - 16;
    gemm_body<0,0>(threadIdx.x, b2 & 15, b2 >> 4, 1, lA, lB, WsynTt, WoB, WsynF,
                   nullptr, nullptr, 1<<30, nullptr, nullptr, nullptr, nullptr,
                   2048, 512, 512, 512, 1536);
  } else {
    int p = blk - 80;                    // 784 = 196bx x 4by
    gemm_body<0,0>(threadIdx.x, p % 196, p / 196, 1, lA, lB, xT, WkvT, kvp0,
                   bkv, bkv, 1<<30, nullptr, nullptr, nullptr, nullptr,
                   MCC_, 512, 512, 512, 512);
  }
}

// permrows + chunk-0 ln_stats in one launch (independent).
__global__ __launch_bounds__(256) void permstats(
    const short* __restrict__ WsynF, short* __restrict__ WsynP,
    const short* __restrict__ kvp0, float* __restrict__ mu0,
    float* __restrict__ iv0)
{
  int blk = blockIdx.x, tid = threadIdx.x;
  if (blk < 2048) {
    int r = blk;
    int k = r >> 4, i = r & 15;
    int src = (i < 8) ? (k*8 + i) : (1024 + k*8 + (i - 8));
    const bf16x8* s = (const bf16x8*)(WsynF + (size_t)src*1536);
    bf16x8* d = (bf16x8*)(WsynP + (size_t)r*1536);
    if (tid < 192) d[tid] = s[tid];
  } else {
    int w = tid >> 6, l = tid & 63;
    int r = (blk-2048)*4 + w;
    if (r >= MCC_) return;
    bf16x8 v8 = *(const bf16x8*)&kvp0[(size_t)r*512 + l*8];
    float s = 0.f, s2 = 0.f;
    #pragma unroll
    for (int j = 0; j < 8; ++j) { float v = b2f(v8[j]); s += v; s2 += v*v; }
    #pragma unroll
    for (int m = 1; m < 64; m <<= 1) { s += __shfl_xor(s, m, 64); s2 += __shfl_xor(s2, m, 64); }
    if (l == 0) {
      float mean = s * (1.f/512.f);
      float var  = s2 * (1.f/512.f) - mean*mean;
      mu0[r] = mean;
      iv0[r] = rsqrtf(var + 1e-5f);
    }
  }
}

// ---------------------------------------------------------------------------
// Piggyback dispatcher (TC_=2 chunk geometry; op index precomputed).
// op4 = x-transpose slice for chunk c+2: 448 blocks x 32 tiles
// op1 = kv-GEMM twin-pair for chunk c+1: 392 pairs = 196bx x 2byp
// op2 = ln_stats: 392 blocks x 64 rows
// op3 = KVT-GEMM twin-pair: 784 pairs = 8bx x 98byp
// ---------------------------------------------------------------------------
__device__ __forceinline__ void run_piggy(int tid, int op, int idx,
    char* pool,
    const float* __restrict__ xg, int t0n1, int t0n2, short* __restrict__ xT,
    const short* __restrict__ WkvT, const float* __restrict__ bkv,
    short* __restrict__ kvpN, float* __restrict__ muN, float* __restrict__ ivN,
    const short* __restrict__ WkkvT, const float* __restrict__ gw,
    const float* __restrict__ bw, short* __restrict__ KVTN, int McN)
{
  if (op == 4) {
    int twin = tid >> 8, tid2 = tid & 255;
    float* tile = (float*)(pool + twin*8448);   // [32][33] f32
    int tx = tid2 & 31, ty = tid2 >> 5;
    int base = idx*32 + twin*16;
    for (int it = 0; it < 16; ++it) {
      int gt = base + it;
      int df0 = (gt & 15) * 32;
      int r = gt >> 4;
      int s0 = (r % 7) * 32;
      int z = r / 7;              // [0,128)
      int b = z >> 1, ti = z & 1;
      const float* src = xg + (size_t)(b*T_ + t0n2 + ti) * DF_ * S_;
      #pragma unroll
      for (int i = 0; i < 4; ++i) {
        int df = df0 + ty + i*8;
        int s  = s0 + tx;
        tile[(ty+i*8)*33 + tx] = (s < S_) ? src[(size_t)df*S_ + s] : 0.f;
      }
      __syncthreads();
      short* dst = xT + (size_t)((t0n2 + ti)*B_ + b) * S_ * DIN_;
      #pragma unroll
      for (int i = 0; i < 4; ++i) {
        int s  = s0 + ty + i*8;
        int df = df0 + tx;
        if (s < S_) dst[(size_t)s*DF_ + df] = f2b(tile[tx*33 + ty+i*8]);
      }
      __syncthreads();
    }
  } else if (op == 1) {
    int twin = tid >> 8;
    short* lA = (short*)pool;
    short* lB = (short*)(pool + 16384 + 16384*twin);
    int p = idx; if (p > 391) p = 391;
    int bx = p % 196, byp = p / 196;
    const short* xTn = xT + (size_t)t0n1 * MR_ * 512;
    gemm_body<0,0>(tid & 255, bx, byp*2 + twin, twin == 0, lA, lB,
                   xTn, WkvT, kvpN, bkv, bkv, 1 << 30,
                   nullptr, nullptr, nullptr, nullptr,
                   McN, 512, 512, 512, 512);
  } else if (op == 2) {
    int blk = idx;
    int w = tid >> 6, l = tid & 63;
    for (int i = 0; i < 8; ++i) {
      int r = blk*64 + i*8 + w;
      if (r < McN) {
        bf16x8 v8 = *(const bf16x8*)&kvpN[(size_t)r*512 + l*8];
        float s = 0.f, s2 = 0.f;
        #pragma unroll
        for (int j = 0; j < 8; ++j) { float v = b2f(v8[j]); s += v; s2 += v*v; }
        #pragma unroll
        for (int m = 1; m < 64; m <<= 1) { s += __shfl_xor(s, m, 64); s2 += __shfl_xor(s2, m, 64); }
        if (l == 0) {
          float mean = s * (1.f/512.f);
          float var  = s2 * (1.f/512.f) - mean*mean;
          muN[r] = mean;
          ivN[r] = rsqrtf(var + 1e-5f);
        }
      }
    }
  } else if (op == 3) {
    int twin = tid >> 8;
    short* lA = (short*)pool;
    short* lB = (short*)(pool + 16384 + 16384*twin);
    int p = idx; if (p > 783) p = 783;
    int bx = p % 8, byp = p / 8;
    gemm_body<0,2>(tid & 255, bx, byp*2 + twin, twin == 0, lA, lB,
                   WkkvT, kvpN, KVTN, nullptr, nullptr, 0,
                   muN, ivN, gw, bw, 1024, McN, 512, 512, McN);
  }
}

#define PIGGY_ARGS int opA, int pfA, int nA, int opB, int pfB, \
    const float* __restrict__ xg, int t0n1, int t0n2, short* __restrict__ xTg, \
    const short* __restrict__ WkvT, \
    const float* __restrict__ bkv, short* __restrict__ kvpN, \
    float* __restrict__ muN, float* __restrict__ ivN, \
    const short* __restrict__ WkkvT, const float* __restrict__ gw, \
    const float* __restrict__ bw, short* __restrict__ KVTN, int McN
#define PIGGY_BODY(BASE) do { \
    int pb = (int)blockIdx.x - (BASE); \
    int op_, idx_; \
    if (pb < nA) { op_ = opA; idx_ = pfA + pb; } \
    else         { op_ = opB; idx_ = pfB + (pb - nA); } \
    run_piggy(tid, op_, idx_, pool, xg, t0n1, t0n2, xTg, WkvT, bkv, \
              kvpN, muN, ivN, WkkvT, gw, bw, KVTN, McN); \
  } while (0)

// ---------------------------------------------------------------------------
// stageCA: per-batch fused {LN(u)->hist->NLM->outk(t-1)} then attn(t).
// 64 tick blocks (block = batch), 512 threads; piggy blocks >= 64.
// hist layout: histB[b][n][25] (batch-major, contiguous per block).
// ---------------------------------------------------------------------------
__global__ __launch_bounds__(512) void stageCA(
    const float* __restrict__ u,
    const float* __restrict__ gsyn, const float* __restrict__ bln,
    float* __restrict__ histB,
    const float* __restrict__ W1, const float* __restrict__ b1,
    const float* __restrict__ W2, const float* __restrict__ b2,
    const float* __restrict__ init_act,
    float* __restrict__ aa, float* __restrict__ ba,
    const int* __restrict__ li_a, const int* __restrict__ ri_a,
    const float* __restrict__ decay_a,
    const short* __restrict__ WqqB, const float* __restrict__ bqh,
    const short* __restrict__ KVT, int ldkv, int ti,
    short* __restrict__ preb,
    float* __restrict__ ao, float* __restrict__ bo_s,
    const int* __restrict__ li_o, const int* __restrict__ ri_o,
    const float* __restrict__ decay_o,
    const short* __restrict__ WoutB, const float* __restrict__ bout,
    float* __restrict__ out, int t, int dopre, int doattn, PIGGY_ARGS)
{
  __shared__ __attribute__((aligned(16))) char pool[49152];
  const int bid = blockIdx.x, tid = threadIdx.x;
  if (bid < 64) {
    const int b = bid;
    float* actL  = (float*)pool;        // 1024
    float* syncL = actL + 1024;         // 512
    float* wred  = syncL + 512;         // 32
    float* qhL   = wred + 32;           // 512
    float* pL    = qhL + 512;           // 2048
    int w = tid >> 6, l = tid & 63;
    if (dopre) {
      const int tp = t - 1;             // tick being finished
      const int slot = tp % MEM_;
      // ---- LayerNorm over u[b][0:1024] ----
      float v0 = u[b*1024 + tid], v1 = u[b*1024 + 512 + tid];
      float s = v0 + v1, s2 = v0*v0 + v1*v1;
      #pragma unroll
      for (int k = 32; k >= 1; k >>= 1) { s += __shfl_xor(s, k, 64); s2 += __shfl_xor(s2, k, 64); }
      if (l == 0) { wred[w] = s; wred[8+w] = s2; }
      __syncthreads();
      float S = 0.f, S2 = 0.f;
      #pragma unroll
      for (int k = 0; k < 8; ++k) { S += wred[k]; S2 += wred[8+k]; }
      float mean = S * (1.f/1024.f);
      float var  = S2 * (1.f/1024.f) - mean*mean;
      float inv  = rsqrtf(var + 1e-5f);
      float nv0 = (v0 - mean)*inv*gsyn[tid]     + bln[tid];
      float nv1 = (v1 - mean)*inv*gsyn[tid+512] + bln[tid+512];
      // ---- NLM for neurons n0=tid, n1=tid+512 ----
      float h[32];
      {
        const int n = tid;
        float* hb = histB + ((size_t)b*1024 + n)*MEM_;
        #pragma unroll
        for (int j = 0; j < 32; ++j) h[j] = b1[n*32+j];
        #pragma unroll 5
        for (int m = 0; m < MEM_; ++m) {
          int phys = (tp + 1 + m) % MEM_;
          float hv = (m == MEM_-1) ? nv0 : hb[phys];
          const float* wp = &W1[((size_t)n*MEM_ + m)*32];
          #pragma unroll
          for (int j = 0; j < 32; ++j) h[j] += hv * wp[j];
        }
        hb[slot] = nv0;
        float acc = b2[n];
        #pragma unroll
        for (int j = 0; j < 32; ++j) acc += fmaxf(h[j], 0.f) * W2[n*32+j];
        actL[n] = acc;
        preb[(size_t)b*1536 + 512 + n] = f2b(acc);
      }
      {
        const int n = tid + 512;
        float* hb = histB + ((size_t)b*1024 + n)*MEM_;
        #pragma unroll
        for (int j = 0; j < 32; ++j) h[j] = b1[n*32+j];
        #pragma unroll 5
        for (int m = 0; m < MEM_; ++m) {
          int phys = (tp + 1 + m) % MEM_;
          float hv = (m == MEM_-1) ? nv1 : hb[phys];
          const float* wp = &W1[((size_t)n*MEM_ + m)*32];
          #pragma unroll
          for (int j = 0; j < 32; ++j) h[j] += hv * wp[j];
        }
        hb[slot] = nv1;
        float acc = b2[n];
        #pragma unroll
        for (int j = 0; j < 32; ++j) acc += fmaxf(h[j], 0.f) * W2[n*32+j];
        actL[n] = acc;
        preb[(size_t)b*1536 + 512 + n] = f2b(acc);
      }
      __syncthreads();
      // ---- outk(tp) using actL ----
      {
        int j = tid;
        float rr = expf(-clip015(decay_o[j]));
        float prod = actL[li_o[j]] * actL[ri_o[j]];
        float a2 = rr*ao[b*512+j] + prod; ao[b*512+j] = a2;
        float bb2 = rr*bo_s[b*512+j] + 1.f; bo_s[b*512+j] = bb2;
        syncL[j] = a2 * rsqrtf(bb2);
        __syncthreads();
        float a = bout[j];
        #pragma unroll 8
        for (int k = 0; k < 512; ++k) a += syncL[k]*b2f(WoutB[k*512+j]);
        out[((size_t)b*512 + j)*16 + tp] = a;
        float m = a;
        #pragma unroll
        for (int k = 32; k >= 1; k >>= 1) m = fmaxf(m, __shfl_xor(m, k, 64));
        if (l == 0) wred[w] = m;
        __syncthreads();
        float M = wred[0];
        #pragma unroll
        for (int k = 1; k < 8; ++k) M = fmaxf(M, wred[k]);
        float e = expf(a - M);
        float z = e, s1 = e*(a - M);
        #pragma unroll
        for (int k = 32; k >= 1; k >>= 1) { z += __shfl_xor(z, k, 64); s1 += __shfl_xor(s1, k, 64); }
        if (l == 0) { wred[8+w] = z; wred[16+w] = s1; }
        __syncthreads();
        if (tid == 0) {
          float Z = 0.f, S1 = 0.f;
          #pragma unroll
          for (int k = 0; k < 8; ++k) { Z += wred[8+k]; S1 += wred[16+k]; }
          float plp = S1 / Z - logf(Z);
          float ne = -plp * (1.f/logf(512.f));
          out[524288 + (size_t)b*32 + tp]      = ne;
          out[524288 + (size_t)b*32 + 16 + tp] = 1.f - ne;
        }
      }
    } else {
      actL[tid]       = init_act[tid];
      actL[tid + 512] = init_act[tid + 512];
    }
    __syncthreads();
    if (doattn) {
      // ---- attn(t) using actL ----
      int j = tid;
      float rr = expf(-clip015(decay_a[j]));
      float prod = actL[li_a[j]] * actL[ri_a[j]];
      float a2 = rr*aa[b*512+j] + prod; aa[b*512+j] = a2;
      float bb2 = rr*ba[b*512+j] + 1.f;  ba[b*512+j] = bb2;
      syncL[j] = a2 * rsqrtf(bb2);
      __syncthreads();
      float qa = bqh[j];
      #pragma unroll 8
      for (int k = 0; k < 512; ++k) qa += syncL[k]*b2f(WqqB[k*512+j]);
      qhL[j] = qa;
      __syncthreads();
      int h8 = tid >> 6;
      const size_t cb = (size_t)(ti*B_ + b) * S_;
      const short* Kb = KVT + (size_t)(h8*64)*ldkv + cb;
      int s3 = 192 + l; int s3c = s3 < S_ ? s3 : S_-1;
      float sc0=0.f, sc1=0.f, sc2=0.f, sc3=0.f;
      #pragma unroll 8
      for (int d = 0; d < 64; ++d) {
        const short* kr = Kb + (size_t)d*ldkv;
        float qv = qhL[h8*64 + d];
        sc0 += qv * b2f(kr[l]);
        sc1 += qv * b2f(kr[64 + l]);
        sc2 += qv * b2f(kr[128 + l]);
        sc3 += qv * b2f(kr[s3c]);
      }
      sc0 *= 0.125f; sc1 *= 0.125f; sc2 *= 0.125f;
      sc3 = (s3 < S_) ? sc3*0.125f : -1e30f;
      float mx = fmaxf(fmaxf(sc0, sc1), fmaxf(sc2, sc3));
      #pragma unroll
      for (int k = 32; k >= 1; k >>= 1) mx = fmaxf(mx, __shfl_xor(mx, k, 64));
      float p0 = expf(sc0-mx), p1 = expf(sc1-mx), p2 = expf(sc2-mx), p3 = expf(sc3-mx);
      pL[h8*256 + l] = p0; pL[h8*256 + 64+l] = p1;
      pL[h8*256 + 128+l] = p2; pL[h8*256 + 192+l] = p3;
      float ps = p0+p1+p2+p3;
      #pragma unroll
      for (int k = 32; k >= 1; k >>= 1) ps += __shfl_xor(ps, k, 64);
      float inv2 = 1.f / ps;
      __syncthreads();
      const short4v* vrow = (const short4v*)(KVT + (size_t)(512 + h8*64 + l)*ldkv + cb);
      const float* pp = pL + h8*256;
      float ac0=0.f, ac1=0.f, ac2=0.f, ac3=0.f;
      #pragma unroll 7
      for (int c = 0; c < 49; ++c) {
        short4v v4 = vrow[c];
        ac0 += pp[c*4]   * b2f(v4.x);
        ac1 += pp[c*4+1] * b2f(v4.y);
        ac2 += pp[c*4+2] * b2f(v4.z);
        ac3 += pp[c*4+3] * b2f(v4.w);
      }
      float accv = (ac0+ac1)+(ac2+ac3);
      preb[(size_t)b*1536 + h8*64 + l] = f2b(accv * inv2);
    }
  } else {
    PIGGY_BODY(64);
  }
}

// ---------------------------------------------------------------------------
// synglu stage: synapse GEMM + GLU -> u. 128 tick blocks; piggy >= 128.
// ---------------------------------------------------------------------------
__global__ __launch_bounds__(512) void stageB(
    const short* __restrict__ preb, const short* __restrict__ WsynP,
    const float* __restrict__ bsynF, float* __restrict__ u, PIGGY_ARGS)
{
  __shared__ __attribute__((aligned(16))) char pool[49152];
  const int bid = blockIdx.x, tid = threadIdx.x;
  if (bid < 128) {
    f32x4* part = (f32x4*)pool;
    int w = tid >> 6, l = tid & 63;
    int mf = w & 3, kh = w >> 2;
    int arow = mf*16 + (l & 15);
    int kbase = kh*768 + (l >> 4)*8;
    const short* ap = preb + (size_t)arow*1536 + kbase;
    const short* bp = WsynP + (size_t)(bid*16 + (l & 15))*1536 + kbase;
    f32x4 acc = (f32x4){0.f,0.f,0.f,0.f};
    #pragma unroll 4
    for (int ks = 0; ks < 24; ++ks) {
      bf16x8 av = *(const bf16x8*)(ap + ks*32);
      bf16x8 bv = *(const bf16x8*)(bp + ks*32);
      acc = __builtin_amdgcn_mfma_f32_16x16x32_bf16(av, bv, acc, 0, 0, 0);
    }
    part[w*64 + l] = acc;
    __syncthreads();
    if (w < 4) {
      f32x4 o1 = part[w*64 + l], o2 = part[(w+4)*64 + l];
      int c = l & 15;
      int colg = bid*8 + (c & 7);
      float bias = (c < 8) ? bsynF[colg] : bsynF[1024 + colg];
      float tv[4], pv[4];
      #pragma unroll
      for (int r2 = 0; r2 < 4; ++r2) tv[r2] = o1[r2] + o2[r2] + bias;
      #pragma unroll
      for (int r2 = 0; r2 < 4; ++r2) pv[r2] = __shfl_xor(tv[r2], 8, 64);
      if (c < 8) {
        #pragma unroll
        for (int r2 = 0; r2 < 4; ++r2) {
          float uu = tv[r2] * (1.f/(1.f + expf(-pv[r2])));
          int brow = w*16 + (l >> 4)*4 + r2;
          u[brow*1024 + colg] = uu;
        }
      }
    }
  } else {
    PIGGY_BODY(128);
  }
}

// ---------------------------------------------------------------------------
// Standalone transpose of x over [t0, t0+tc) (fallback path).
// ---------------------------------------------------------------------------
__global__ __launch_bounds__(256) void xpose_x(const float* __restrict__ x,
                                               short* __restrict__ xT, int t0, int tc)
{
  __shared__ float tile[32][33];
  int df0 = blockIdx.x*32, s0 = blockIdx.y*32;
  int z = blockIdx.z;
  int b = z / tc, ti = z % tc;
  int tx = threadIdx.x & 31, ty = threadIdx.x >> 5;
  const float* src = x + (size_t)(b*T_ + t0 + ti) * DF_ * S_;
  #pragma unroll
  for (int i = 0; i < 4; ++i) {
    int df = df0 + ty + i*8;
    int s  = s0 + tx;
    tile[ty+i*8][tx] = (s < S_) ? src[(size_t)df*S_ + s] : 0.f;
  }
  __syncthreads();
  short* dst = xT + (size_t)((t0 + ti)*B_ + b) * S_ * DIN_;
  #pragma unroll
  for (int i = 0; i < 4; ++i) {
    int s  = s0 + ty + i*8;
    int df = df0 + tx;
    if (s < S_) dst[(size_t)s*DF_ + df] = f2b(tile[tx][ty+i*8]);
  }
}

// Standalone per-row LN stats (fallback path).
__global__ __launch_bounds__(256) void ln_stats(const short* __restrict__ in,
    float* __restrict__ mu, float* __restrict__ iv, int nrows)
{
  int w = threadIdx.x >> 6, l = threadIdx.x & 63;
  int r = blockIdx.x*4 + w;
  if (r >= nrows) return;
  bf16x8 v8 = *(const bf16x8*)&in[(size_t)r*512 + l*8];
  float s = 0.f, s2 = 0.f;
  #pragma unroll
  for (int j = 0; j < 8; ++j) { float v = b2f(v8[j]); s += v; s2 += v*v; }
  #pragma unroll
  for (int m = 1; m < 64; m <<= 1) { s += __shfl_xor(s, m, 64); s2 += __shfl_xor(s2, m, 64); }
  if (l == 0) {
    float mean = s * (1.f/512.f);
    float var  = s2 * (1.f/512.f) - mean*mean;
    mu[r] = mean;
    iv[r] = rsqrtf(var + 1e-5f);
  }
}

// ---------------------------------------------------------------------------
// prep_all: weight transposes, casts, bias folds, state init AND the
// xpose of ticks 0..3 (chunks 0-1), all in one launch.
// histB layout: [b][n][25]  ->  histB[i] = init_hist[i % 25600].
// ---------------------------------------------------------------------------
__global__ __launch_bounds__(256) void prep_all(
    const float* __restrict__ Wkv, const float* __restrict__ Wk,
    const float* __restrict__ Wv,  const float* __restrict__ Wsyn,
    const float* __restrict__ Wq,  const float* __restrict__ Wqp,
    const float* __restrict__ Wo,  const float* __restrict__ Wout,
    const float* __restrict__ g_kv, const float* __restrict__ b_kv,
    const float* __restrict__ bk, const float* __restrict__ bv,
    const float* __restrict__ bqp, const float* __restrict__ bq,
    const float* __restrict__ bo_p, const float* __restrict__ bsyn,
    short* __restrict__ WkvT, short* __restrict__ WkkvT,
    short* __restrict__ WsynF, short* __restrict__ WsynTt,
    short* __restrict__ WqT, short* __restrict__ WqpB,
    short* __restrict__ WoB, short* __restrict__ WoutB,
    float* __restrict__ bqh, float* __restrict__ bsynF,
    float* __restrict__ gw, float* __restrict__ bw,
    float* __restrict__ aa, float* __restrict__ ba,
    float* __restrict__ ao, float* __restrict__ bo_s,
    float* __restrict__ histB, short* __restrict__ preb,
    const float* __restrict__ init_act, const float* __restrict__ init_hist,
    const int* __restrict__ li_o, const int* __restrict__ ri_o,
    const float* __restrict__ x, short* __restrict__ xT)
{
  __shared__ float tile[32][33];
  const int blk = blockIdx.x, tid = threadIdx.x;
  auto wtr = [&](const float* in, short* out, int bx, int by,
                 int C, int ldo, int coff, const float* scale){
    int c0 = bx*32, r0 = by*32;
    int tx = tid & 31, ty = tid >> 5;
    #pragma unroll
    for (int i = 0; i < 4; ++i) {
      int r = r0+ty+i*8;
      float sc = scale ? scale[r] : 1.f;
      tile[ty+i*8][tx] = in[(size_t)r*C + c0+tx] * sc;
    }
    __syncthreads();
    #pragma unroll
    for (int i = 0; i < 4; ++i)
      out[(size_t)(c0+ty+i*8)*ldo + coff + r0+tx] = f2b(tile[tx][ty+i*8]);
  };
  auto cvt4 = [&](const float* in, short* out, int sb){
    int i = (sb*256 + tid)*4;
    #pragma unroll
    for (int j = 0; j < 4; ++j) out[i+j] = f2b(in[i+j]);
  };
  auto bfold = [&](const float* vec, const float* W, const float* base,
                   float* out, int n, int ldw){
    float a = base ? base[n] : 0.f;
    #pragma unroll 8
    for (int k = 0; k < 512; ++k) a += vec[k]*W[(size_t)k*ldw + n];
    out[n] = a;
  };

  if (blk < 256)       wtr(Wkv, WkvT, blk & 15, blk >> 4, 512, 512, 0, nullptr);
  else if (blk < 512)  { int s = blk-256;  wtr(Wk, WkkvT, s & 15, s >> 4, 512, 512, 0, g_kv); }
  else if (blk < 768)  { int s = blk-512;  wtr(Wv, WkkvT + (size_t)512*512, s & 15, s >> 4, 512, 512, 0, g_kv); }
  else if (blk < 2816) { int s = blk-768;  wtr(Wsyn + (size_t)512*2048, WsynF, s % 64, s / 64, 2048, 1536, 512, nullptr); }
  else if (blk < 3840) { int s = blk-2816; wtr(Wsyn, WsynTt, s % 64, s / 64, 2048, 512, 0, nullptr); }
  else if (blk < 4096) { int s = blk-3840; wtr(Wq, WqT, s & 15, s >> 4, 512, 512, 0, nullptr); }
  else if (blk < 4352) cvt4(Wqp,  WqpB,  blk-4096);
  else if (blk < 4608) cvt4(Wo,   WoB,   blk-4352);
  else if (blk < 4864) cvt4(Wout, WoutB, blk-4608);
  else if (blk < 4882) {
    int j = blk-4864;
    if (j < 2)        bfold(bqp,  Wq,   bq,   bqh,   j*256 + tid,      512);
    else if (j < 10)  bfold(bo_p, Wsyn, bsyn, bsynF, (j-2)*256 + tid,  2048);
    else if (j < 12)  bfold(g_kv, Wk,   nullptr, gw,       (j-10)*256 + tid, 512);
    else if (j < 14)  bfold(g_kv, Wv,   nullptr, gw + 512, (j-12)*256 + tid, 512);
    else if (j < 16)  bfold(b_kv, Wk,   bk,   bw,       (j-14)*256 + tid, 512);
    else              bfold(b_kv, Wv,   bv,   bw + 512, (j-16)*256 + tid, 512);
  } else if (blk < 11282) {
    int i = (blk-4882)*256 + tid;
    if (i < 64*512) {
      aa[i] = 0.f; ba[i] = 0.f;
      int j = i & 511;
      ao[i] = init_act[li_o[j]] * init_act[ri_o[j]];
      bo_s[i] = 1.f;
    }
    if (i < 65536) {
      int n = i >> 6, b = i & 63;
      preb[(size_t)b*1536 + 512 + n] = f2b(init_act[n]);
    }
    if (i < DM_*MEM_*64) {
      histB[i] = init_hist[i % 25600];
    }
  } else {
    // xpose ticks 0..3: 1792 blocks x 16 tiles = 28672 = 16df x 7s x 256(b,t)
    int tx = tid & 31, ty = tid >> 5;
    int base = (blk - 11282) * 16;
    for (int it = 0; it < 16; ++it) {
      int gt = base + it;
      int df0 = (gt & 15) * 32;
      int r = gt >> 4;
      int s0 = (r % 7) * 32;
      int z = r / 7;              // [0,256)
      int b = z >> 2, t = z & 3;
      const float* src = x + (size_t)(b*T_ + t) * DF_ * S_;
      #pragma unroll
      for (int i = 0; i < 4; ++i) {
        int df = df0 + ty + i*8;
        int s  = s0 + tx;
        tile[ty+i*8][tx] = (s < S_) ? src[(size_t)df*S_ + s] : 0.f;
      }
      __syncthreads();
      short* dst = xT + (size_t)(t*B_ + b) * S_ * DIN_;
      #pragma unroll
      for (int i = 0; i < 4; ++i) {
        int s  = s0 + ty + i*8;
        int df = df0 + tx;
        if (s < S_) dst[(size_t)s*DF_ + df] = f2b(tile[tx][ty+i*8]);
      }
      __syncthreads();
    }
  }
}

// ---------------------------------------------------------------------------
extern "C" void kernel_launch(void* const* d_in, const int* in_sizes, int n_in,
                              void* d_out, int out_size, void* d_ws, size_t ws_size,
                              hipStream_t stream)
{
  (void)in_sizes; (void)n_in; (void)out_size;
  const float* x       = (const float*)d_in[0];
  const float* Wqp     = (const float*)d_in[1];
  const float* bqp     = (const float*)d_in[2];
  const float* Wkv     = (const float*)d_in[3];
  const float* bkv     = (const float*)d_in[4];
  const float* g_kv    = (const float*)d_in[5];
  const float* b_kv    = (const float*)d_in[6];
  const float* Wq      = (const float*)d_in[7];
  const float* bq      = (const float*)d_in[8];
  const float* Wk      = (const float*)d_in[9];
  const float* bk      = (const float*)d_in[10];
  const float* Wv      = (const float*)d_in[11];
  const float* bv      = (const float*)d_in[12];
  const float* Wo      = (const float*)d_in[13];
  const float* bo_p    = (const float*)d_in[14];
  const float* Wsyn    = (const float*)d_in[15];
  const float* bsyn    = (const float*)d_in[16];
  const float* g_syn   = (const float*)d_in[17];
  const float* b_syn   = (const float*)d_in[18];
  const float* W1      = (const float*)d_in[19];
  const float* b1      = (const float*)d_in[20];
  const float* W2      = (const float*)d_in[21];
  const float* b2      = (const float*)d_in[22];
  const float* init_act  = (const float*)d_in[23];
  const float* init_hist = (const float*)d_in[24];
  const float* decay_a = (const float*)d_in[25];
  const float* decay_o = (const float*)d_in[26];
  const float* Wout    = (const float*)d_in[27];
  const float* bout    = (const float*)d_in[28];
  const int* li_a = (const int*)d_in[29];
  const int* ri_a = (const int*)d_in[30];
  const int* li_o = (const int*)d_in[31];
  const int* ri_o = (const int*)d_in[32];

  char* ws = (char*)d_ws;
  size_t off = 0;
  auto alloc = [&](size_t bytes) { char* p = ws + off; off += (bytes + 255) & ~(size_t)255; return p; };
  short* WkvT   = (short*)alloc(512*512*2);
  short* WkkvT  = (short*)alloc(1024*512*2);
  short* WsynF  = (short*)alloc(2048*1536*2);
  short* WsynP  = (short*)alloc(2048*1536*2);
  short* WsynTt = (short*)alloc(2048*512*2);
  short* WqpB   = (short*)alloc(512*512*2);
  short* WqT    = (short*)alloc(512*512*2);
  short* WoB    = (short*)alloc(512*512*2);
  short* WqqB   = (short*)alloc(512*512*2);
  short* WoutB  = (short*)alloc(512*512*2);
  float* bqh    = (float*)alloc(512*4);
  float* bsynF  = (float*)alloc(2048*4);
  float* gw     = (float*)alloc(1024*4);
  float* bw     = (float*)alloc(1024*4);
  short* preb   = (short*)alloc(64*1536*2);
  float* u      = (float*)alloc(64*1024*4);
  float* aa     = (float*)alloc(64*512*4);
  float* ba     = (float*)alloc(64*512*4);
  float* ao     = (float*)alloc(64*512*4);
  float* bo_s   = (float*)alloc(64*512*4);
  float* histB  = (float*)alloc((size_t)64*1024*25*4);
  size_t fixed_end = off;

  const size_t szXT  = (size_t)T_*MR_*512*2;     // 205.5 MB (all 16 ticks)
  const size_t szKVP = (size_t)MCC_*512*2;       //  25.7 MB per chunk
  const size_t szKVT = (size_t)MCC_*1024*2;      //  51.4 MB per chunk
  const size_t szST  = (size_t)MCC_*4;
  size_t need_full = fixed_end + szXT + 2*szKVP + 2*szKVT + 4*szST + 4096;
  bool pig_en = (ws_size >= need_full);

  short* xT = (short*)alloc(szXT);
  short* kvpB[2]; short* KVTB[2]; float* muB[2]; float* ivB[2];
  kvpB[0] = (short*)alloc(szKVP);
  KVTB[0] = (short*)alloc(szKVT);
  muB[0]  = (float*)alloc(szST);
  ivB[0]  = (float*)alloc(szST);
  if (pig_en) {
    kvpB[1] = (short*)alloc(szKVP);
    KVTB[1] = (short*)alloc(szKVT);
    muB[1]  = (float*)alloc(szST);
    ivB[1]  = (float*)alloc(szST);
  } else {
    kvpB[1] = kvpB[0]; KVTB[1] = KVTB[0]; muB[1] = muB[0]; ivB[1] = ivB[0];
  }

  const int BIG = 1 << 30;
  const float* FN = nullptr;

  prep_all<<<13074, 256, 0, stream>>>(Wkv, Wk, Wv, Wsyn, Wq, Wqp, Wo, Wout,
      g_kv, b_kv, bk, bv, bqp, bq, bo_p, bsyn,
      WkvT, WkkvT, WsynF, WsynTt, WqT, WqpB, WoB, WoutB,
      bqh, bsynF, gw, bw, aa, ba, ao, bo_s, histB, preb,
      init_act, init_hist, li_o, ri_o, x, xT);
  if (!pig_en)
    xpose_x<<<dim3(16,7,B_*(T_-2*TC_)), 256, 0, stream>>>(x, xT, 2*TC_, T_-2*TC_);
  gemm_prep3<<<864, 256, 0, stream>>>(WqpB, WqT, WqqB, WsynTt, WoB, WsynF,
                                      xT, WkvT, bkv, kvpB[0]);
  permstats<<<2048 + MCC_/4, 256, 0, stream>>>(WsynF, WsynP, kvpB[0], muB[0], ivB[0]);
  gemm_k<0,2><<<dim3(8,196), 256, 0, stream>>>(WkkvT, kvpB[0], KVTB[0], nullptr, nullptr, BIG,
                                               muB[0], ivB[0], gw, bw, 1024, MCC_, 512, 512, MCC_);

  auto run_pipe = [&](int c, short* kvpP, float* muP, float* ivP, short* KVTP){
    const short* xTc = xT + (size_t)c*TC_*MR_*512;
    gemm_k<0,0><<<dim3(196,4), 256, 0, stream>>>(xTc, WkvT, kvpP, bkv, bkv, BIG,
                                                 FN, FN, FN, FN, MCC_, 512, 512, 512, 512);
    ln_stats<<<MCC_/4, 256, 0, stream>>>(kvpP, muP, ivP, MCC_);
    gemm_k<0,2><<<dim3(8,196), 256, 0, stream>>>(WkkvT, kvpP, KVTP, nullptr, nullptr, BIG,
                                                 muP, ivP, gw, bw, 1024, MCC_, 512, 512, MCC_);
  };

  // per-chunk piggy schedule over 4 tail slots:
  // q0 (stageCA ti=0): op1(392); q1 (stageB ti=0): op2(392)+op4a(224);
  // q2 (stageCA ti=1): op3a(392)+op4b(224); q3 (stageB ti=1): op3b(392).
  auto pigcfg = [](int q, bool p123, bool p4,
                   int& opA, int& pfA, int& nA, int& opB, int& pfB, int& nB){
    opA = 0; pfA = 0; nA = 0; opB = 0; pfB = 0; nB = 0;
    if (q == 0)      { if (p123) { opA = 1; pfA = 0;   nA = 392; } }
    else if (q == 1) { if (p123) { opA = 2; pfA = 0;   nA = 392; }
                       if (p4)   { opB = 4; pfB = 0;   nB = 224; } }
    else if (q == 2) { if (p123) { opA = 3; pfA = 0;   nA = 392; }
                       if (p4)   { opB = 4; pfB = 224; nB = 224; } }
    else             { if (p123) { opA = 3; pfA = 392; nA = 392; } }
  };

  for (int c = 0; c < NCH_; ++c) {
    int par = pig_en ? (c & 1) : 0;
    int nxt = pig_en ? (par ^ 1) : 0;
    if (!pig_en && c > 0) run_pipe(c, kvpB[0], muB[0], ivB[0], KVTB[0]);
    bool p123 = pig_en && (c < NCH_-1);
    bool p4   = pig_en && (c < NCH_-2);
    int t0n1 = (c < NCH_-1) ? (c+1)*TC_ : 0;
    int t0n2 = (c < NCH_-2) ? (c+2)*TC_ : 0;
    for (int ti = 0; ti < TC_; ++ti) {
      int t = c*TC_ + ti;
      int oA, fA, nA, oB, fB, nB;
      pigcfg(ti*2+0, p123, p4, oA, fA, nA, oB, fB, nB);
      stageCA<<<64+nA+nB, 512, 0, stream>>>(u, g_syn, b_syn, histB,
          W1, b1, W2, b2, init_act,
          aa, ba, li_a, ri_a, decay_a, WqqB, bqh, KVTB[par], MCC_, ti, preb,
          ao, bo_s, li_o, ri_o, decay_o, WoutB, bout, (float*)d_out,
          t, (t > 0) ? 1 : 0, 1,
          oA, fA, nA, oB, fB, x, t0n1, t0n2, xT, WkvT, bkv,
          kvpB[nxt], muB[nxt], ivB[nxt], WkkvT, gw, bw, KVTB[nxt], MCC_);
      pigcfg(ti*2+1, p123, p4, oA, fA, nA, oB, fB, nB);
      stageB<<<128+nA+nB, 512, 0, stream>>>(preb, WsynP, bsynF, u,
          oA, fA, nA, oB, fB, x, t0n1, t0n2, xT, WkvT, bkv,
          kvpB[nxt], muB[nxt], ivB[nxt], WkkvT, gw, bw, KVTB[nxt], MCC_);
    }
  }
  // final: finish tick 15 (LN+NLM+outk), no attention.
  stageCA<<<64, 512, 0, stream>>>(u, g_syn, b_syn, histB,
      W1, b1, W2, b2, init_act,
      aa, ba, li_a, ri_a, decay_a, WqqB, bqh, KVTB[(NCH_-1)&1], MCC_, 1, preb,
      ao, bo_s, li_o, ri_o, decay_o, WoutB, bout, (float*)d_out,
      T_, 1, 0,
      0, 0, 0, 0, 0, x, 0, 0, xT, WkvT, bkv,
      kvpB[0], muB[0], ivB[0], WkkvT, gw, bw, KVTB[0], MCC_);
}

// Round 15
// 2041.735 us; speedup vs baseline: 1.5920x; 1.5920x over previous
//
#include <hip/hip_runtime.h>
#include <stdint.h>
#include <stddef.h>

#define B_    64
#define T_    16
#define DF_   512
#define S_    196
#define DIN_  512
#define H_    8
#define DH_   64
#define DM_   1024
#define MEM_  25
#define HN_   32
#define MR_   (B_*S_)     /* 12544 rows per tick */
#define TC_   2           /* ticks per chunk */
#define NCH_  (T_/TC_)    /* 8 chunks */
#define MCC_  (MR_*TC_)   /* 25088 rows per chunk */

typedef short bf16x8 __attribute__((ext_vector_type(8)));
typedef short short4v __attribute__((ext_vector_type(4)));
typedef float f32x4  __attribute__((ext_vector_type(4)));

__device__ __forceinline__ float b2f(short h){
  unsigned u = ((unsigned)(unsigned short)h) << 16;
  float f; __builtin_memcpy(&f, &u, 4); return f;
}
__device__ __forceinline__ short f2b(float f){
  unsigned u; __builtin_memcpy(&u, &f, 4);
  u = (u + 0x7fffu + ((u >> 16) & 1u)) >> 16;
  return (short)(unsigned short)u;
}
__device__ __forceinline__ float clip015(float d){
  return d < 0.f ? 0.f : (d > 15.f ? 15.f : d);
}

// ---------------------------------------------------------------------------
// bf16 MFMA GEMM body (verified R8..R12 code). 128x128 tile, BK=64, 4 waves
// 2x2 over tid 0..255, 16x16x32 MFMA, global_load_lds width-16, XOR chunk
// swizzle. aload=0 lets a twin block skip A-tile loads (shared lA).
// LNEPI=0: +bias. LNEPI=2: transposed-LN fold (col stats, row gw/bw).
// No spins / unbounded waits anywhere in this file: every kernel terminates.
// ---------------------------------------------------------------------------
template<int OUTF32, int LNEPI>
__device__ __forceinline__ void gemm_body(int tid, int bx, int by, int aload,
    short* lA, short* lB,
    const short* __restrict__ A, const short* __restrict__ WT,
    void* __restrict__ Cout,
    const float* __restrict__ biasA, const float* __restrict__ biasB, int nsplit,
    const float* __restrict__ mu, const float* __restrict__ iv,
    const float* __restrict__ gw, const float* __restrict__ bw,
    int M, int N, int K, int lda, int ldc)
{
  const int w = tid >> 6, l = tid & 63;
  const int m0 = bx * 128, n0 = by * 128;
  const int wm = (w >> 1) * 64, wn = (w & 1) * 64;
  f32x4 acc[4][4];
  #pragma unroll
  for (int i=0;i<4;i++)
    #pragma unroll
    for (int j=0;j<4;j++) acc[i][j] = (f32x4){0.f,0.f,0.f,0.f};

  for (int k0 = 0; k0 < K; k0 += 64) {
    #pragma unroll
    for (int rnd = 0; rnd < 4; ++rnd) {
      int cb = (rnd*4 + w) * 64;
      int slot = cb + l;
      int row = slot >> 3, kb = slot & 7;
      int kc = k0 + ((kb ^ (row & 7)) << 3);
      if (aload) {
        int gm = m0 + row; if (gm > M-1) gm = M-1;
        __builtin_amdgcn_global_load_lds(
            (const __attribute__((address_space(1))) void*)(A + (size_t)gm * lda + kc),
            (__attribute__((address_space(3))) void*)&lA[cb*8], 16, 0, 0);
      }
      __builtin_amdgcn_global_load_lds(
          (const __attribute__((address_space(1))) void*)(WT + (size_t)(n0 + row) * K + kc),
          (__attribute__((address_space(3))) void*)&lB[cb*8], 16, 0, 0);
    }
    asm volatile("s_waitcnt vmcnt(0)" ::: "memory");
    __syncthreads();
    #pragma unroll
    for (int ks = 0; ks < 2; ++ks) {
      bf16x8 af[4], bfr[4];
      #pragma unroll
      for (int i = 0; i < 4; ++i) {
        int ra = wm + i*16 + (l & 15);
        int c  = ks*4 + (l >> 4);
        af[i]  = *(const bf16x8*)&lA[ra*64 + ((c ^ (ra & 7)) << 3)];
        int rb = wn + i*16 + (l & 15);
        bfr[i] = *(const bf16x8*)&lB[rb*64 + ((c ^ (rb & 7)) << 3)];
      }
      #pragma unroll
      for (int i = 0; i < 4; ++i)
        #pragma unroll
        for (int j = 0; j < 4; ++j)
          acc[i][j] = __builtin_amdgcn_mfma_f32_16x16x32_bf16(af[i], bfr[j], acc[i][j], 0, 0, 0);
    }
    __syncthreads();
  }
  #pragma unroll
  for (int i = 0; i < 4; ++i) {
    #pragma unroll
    for (int j = 0; j < 4; ++j) {
      int gn = n0 + wn + j*16 + (l & 15);
      float ivn = 0.f, mun = 0.f, bb = 0.f;
      if (LNEPI == 2) { ivn = iv[gn]; mun = mu[gn]; }
      else bb = biasA ? ((gn < nsplit) ? biasA[gn] : biasB[gn - nsplit]) : 0.f;
      #pragma unroll
      for (int r = 0; r < 4; ++r) {
        int gm = m0 + wm + i*16 + (l >> 4)*4 + r;
        if (gm < M) {
          float v;
          if (LNEPI == 2) v = ivn*(acc[i][j][r] - mun*gw[gm]) + bw[gm];
          else            v = acc[i][j][r] + bb;
          if (OUTF32) ((float*)Cout)[(size_t)gm * ldc + gn] = v;
          else        ((short*)Cout)[(size_t)gm * ldc + gn] = f2b(v);
        }
      }
    }
  }
}

// Standalone 256-thread GEMM kernel (chunk-0 KVT / fallback).
template<int OUTF32, int LNEPI>
__global__ __launch_bounds__(256,2) void gemm_k(
    const short* __restrict__ A, const short* __restrict__ WT,
    void* __restrict__ Cout,
    const float* __restrict__ biasA, const float* __restrict__ biasB, int nsplit,
    const float* __restrict__ mu, const float* __restrict__ iv,
    const float* __restrict__ gw, const float* __restrict__ bw,
    int M, int N, int K, int lda, int ldc)
{
  __shared__ short lA[128*64];
  __shared__ short lB[128*64];
  gemm_body<OUTF32,LNEPI>(threadIdx.x, blockIdx.x, blockIdx.y, 1, lA, lB,
                          A, WT, Cout, biasA, biasB, nsplit, mu, iv, gw, bw,
                          M, N, K, lda, ldc);
}

// Both weight-fold GEMMs + chunk-0 kv GEMM in one launch (independent).
__global__ __launch_bounds__(256,2) void gemm_prep3(
    const short* __restrict__ WqpB, const short* __restrict__ WqT,
    short* __restrict__ WqqB,
    const short* __restrict__ WsynTt, const short* __restrict__ WoB,
    short* __restrict__ WsynF,
    const short* __restrict__ xT, const short* __restrict__ WkvT,
    const float* __restrict__ bkv, short* __restrict__ kvp0)
{
  __shared__ short lA[128*64];
  __shared__ short lB[128*64];
  int blk = blockIdx.x;
  if (blk < 16)
    gemm_body<0,0>(threadIdx.x, blk & 3, blk >> 2, 1, lA, lB, WqpB, WqT, WqqB,
                   nullptr, nullptr, 1<<30, nullptr, nullptr, nullptr, nullptr,
                   512, 512, 512, 512, 512);
  else if (blk < 80) {
    int b2 = blk - 16;
    gemm_body<0,0>(threadIdx.x, b2 & 15, b2 >> 4, 1, lA, lB, WsynTt, WoB, WsynF,
                   nullptr, nullptr, 1<<30, nullptr, nullptr, nullptr, nullptr,
                   2048, 512, 512, 512, 1536);
  } else {
    int p = blk - 80;                    // 784 = 196bx x 4by
    gemm_body<0,0>(threadIdx.x, p % 196, p / 196, 1, lA, lB, xT, WkvT, kvp0,
                   bkv, bkv, 1<<30, nullptr, nullptr, nullptr, nullptr,
                   MCC_, 512, 512, 512, 512);
  }
}

// permrows + chunk-0 ln_stats in one launch (independent).
__global__ __launch_bounds__(256) void permstats(
    const short* __restrict__ WsynF, short* __restrict__ WsynP,
    const short* __restrict__ kvp0, float* __restrict__ mu0,
    float* __restrict__ iv0)
{
  int blk = blockIdx.x, tid = threadIdx.x;
  if (blk < 2048) {
    int r = blk;
    int k = r >> 4, i = r & 15;
    int src = (i < 8) ? (k*8 + i) : (1024 + k*8 + (i - 8));
    const bf16x8* s = (const bf16x8*)(WsynF + (size_t)src*1536);
    bf16x8* d = (bf16x8*)(WsynP + (size_t)r*1536);
    if (tid < 192) d[tid] = s[tid];
  } else {
    int w = tid >> 6, l = tid & 63;
    int r = (blk-2048)*4 + w;
    if (r >= MCC_) return;
    bf16x8 v8 = *(const bf16x8*)&kvp0[(size_t)r*512 + l*8];
    float s = 0.f, s2 = 0.f;
    #pragma unroll
    for (int j = 0; j < 8; ++j) { float v = b2f(v8[j]); s += v; s2 += v*v; }
    #pragma unroll
    for (int m = 1; m < 64; m <<= 1) { s += __shfl_xor(s, m, 64); s2 += __shfl_xor(s2, m, 64); }
    if (l == 0) {
      float mean = s * (1.f/512.f);
      float var  = s2 * (1.f/512.f) - mean*mean;
      mu0[r] = mean;
      iv0[r] = rsqrtf(var + 1e-5f);
    }
  }
}

// ---------------------------------------------------------------------------
// Piggyback dispatcher (TC_=2 chunk geometry; op index precomputed).
// op4 = x-transpose slice for chunk c+2: 448 blocks x 32 tiles = 14336
// op1 = kv-GEMM twin-pair for chunk c+1: 392 pairs = 196bx x 2byp
// op2 = ln_stats: 392 blocks x 64 rows = 25088
// op3 = KVT-GEMM twin-pair: 784 pairs = 8bx x 98byp
// ---------------------------------------------------------------------------
__device__ __forceinline__ void run_piggy(int tid, int op, int idx,
    char* pool,
    const float* __restrict__ xg, int t0n1, int t0n2, short* __restrict__ xT,
    const short* __restrict__ WkvT, const float* __restrict__ bkv,
    short* __restrict__ kvpN, float* __restrict__ muN, float* __restrict__ ivN,
    const short* __restrict__ WkkvT, const float* __restrict__ gw,
    const float* __restrict__ bw, short* __restrict__ KVTN, int McN)
{
  if (op == 4) {
    int twin = tid >> 8, tid2 = tid & 255;
    float* tile = (float*)(pool + twin*8448);   // [32][33] f32
    int tx = tid2 & 31, ty = tid2 >> 5;
    int base = idx*32 + twin*16;
    for (int it = 0; it < 16; ++it) {
      int gt = base + it;
      int df0 = (gt & 15) * 32;
      int r = gt >> 4;
      int s0 = (r % 7) * 32;
      int z = r / 7;              // [0,128)
      int b = z >> 1, ti = z & 1;
      const float* src = xg + (size_t)(b*T_ + t0n2 + ti) * DF_ * S_;
      #pragma unroll
      for (int i = 0; i < 4; ++i) {
        int df = df0 + ty + i*8;
        int s  = s0 + tx;
        tile[(ty+i*8)*33 + tx] = (s < S_) ? src[(size_t)df*S_ + s] : 0.f;
      }
      __syncthreads();
      short* dst = xT + (size_t)((t0n2 + ti)*B_ + b) * S_ * DIN_;
      #pragma unroll
      for (int i = 0; i < 4; ++i) {
        int s  = s0 + ty + i*8;
        int df = df0 + tx;
        if (s < S_) dst[(size_t)s*DF_ + df] = f2b(tile[tx*33 + ty+i*8]);
      }
      __syncthreads();
    }
  } else if (op == 1) {
    int twin = tid >> 8;
    short* lA = (short*)pool;
    short* lB = (short*)(pool + 16384 + 16384*twin);
    int p = idx; if (p > 391) p = 391;
    int bx = p % 196, byp = p / 196;
    const short* xTn = xT + (size_t)t0n1 * MR_ * 512;
    gemm_body<0,0>(tid & 255, bx, byp*2 + twin, twin == 0, lA, lB,
                   xTn, WkvT, kvpN, bkv, bkv, 1 << 30,
                   nullptr, nullptr, nullptr, nullptr,
                   McN, 512, 512, 512, 512);
  } else if (op == 2) {
    int blk = idx;
    int w = tid >> 6, l = tid & 63;
    for (int i = 0; i < 8; ++i) {
      int r = blk*64 + i*8 + w;
      if (r < McN) {
        bf16x8 v8 = *(const bf16x8*)&kvpN[(size_t)r*512 + l*8];
        float s = 0.f, s2 = 0.f;
        #pragma unroll
        for (int j = 0; j < 8; ++j) { float v = b2f(v8[j]); s += v; s2 += v*v; }
        #pragma unroll
        for (int m = 1; m < 64; m <<= 1) { s += __shfl_xor(s, m, 64); s2 += __shfl_xor(s2, m, 64); }
        if (l == 0) {
          float mean = s * (1.f/512.f);
          float var  = s2 * (1.f/512.f) - mean*mean;
          muN[r] = mean;
          ivN[r] = rsqrtf(var + 1e-5f);
        }
      }
    }
  } else if (op == 3) {
    int twin = tid >> 8;
    short* lA = (short*)pool;
    short* lB = (short*)(pool + 16384 + 16384*twin);
    int p = idx; if (p > 783) p = 783;
    int bx = p % 8, byp = p / 8;
    gemm_body<0,2>(tid & 255, bx, byp*2 + twin, twin == 0, lA, lB,
                   WkkvT, kvpN, KVTN, nullptr, nullptr, 0,
                   muN, ivN, gw, bw, 1024, McN, 512, 512, McN);
  }
}

// ---------------------------------------------------------------------------
// Tick bodies (verified R8..R12 logic, pool-based LDS).
// ---------------------------------------------------------------------------
__device__ __forceinline__ void attn_body(int b, int tid, float* smem,
    const float* actT, float* aa, float* ba,
    const int* li_a, const int* ri_a, const float* decay_a,
    const short* WqqB, const float* bqh,
    const short* KVT, int ldkv, int ti, short* preb)
{
  float* syncL = smem;
  float* qhL   = smem + 512;
  float* pL    = smem + 1024;   // 8*256
  int j = tid;
  float rr = expf(-clip015(decay_a[j]));
  float prod = actT[li_a[j]*64 + b] * actT[ri_a[j]*64 + b];
  float a2 = rr*aa[b*512+j] + prod; aa[b*512+j] = a2;
  float bb2 = rr*ba[b*512+j] + 1.f;  ba[b*512+j] = bb2;
  syncL[j] = a2 * rsqrtf(bb2);
  __syncthreads();
  float qa = bqh[j];
  #pragma unroll 8
  for (int k = 0; k < 512; ++k) qa += syncL[k]*b2f(WqqB[k*512+j]);
  qhL[j] = qa;
  __syncthreads();
  int h = tid >> 6, l = tid & 63;
  const size_t cb = (size_t)(ti*B_ + b) * S_;
  const short* Kb = KVT + (size_t)(h*64)*ldkv + cb;
  int s3 = 192 + l; int s3c = s3 < S_ ? s3 : S_-1;
  float sc0=0.f, sc1=0.f, sc2=0.f, sc3=0.f;
  #pragma unroll 8
  for (int d = 0; d < 64; ++d) {
    const short* kr = Kb + (size_t)d*ldkv;
    float qv = qhL[h*64 + d];
    sc0 += qv * b2f(kr[l]);
    sc1 += qv * b2f(kr[64 + l]);
    sc2 += qv * b2f(kr[128 + l]);
    sc3 += qv * b2f(kr[s3c]);
  }
  sc0 *= 0.125f; sc1 *= 0.125f; sc2 *= 0.125f;
  sc3 = (s3 < S_) ? sc3*0.125f : -1e30f;
  float mx = fmaxf(fmaxf(sc0, sc1), fmaxf(sc2, sc3));
  #pragma unroll
  for (int k = 32; k >= 1; k >>= 1) mx = fmaxf(mx, __shfl_xor(mx, k, 64));
  float p0 = expf(sc0-mx), p1 = expf(sc1-mx), p2 = expf(sc2-mx), p3 = expf(sc3-mx);
  pL[h*256 + l] = p0; pL[h*256 + 64+l] = p1;
  pL[h*256 + 128+l] = p2; pL[h*256 + 192+l] = p3;
  float ps = p0+p1+p2+p3;
  #pragma unroll
  for (int k = 32; k >= 1; k >>= 1) ps += __shfl_xor(ps, k, 64);
  float inv = 1.f / ps;
  __syncthreads();
  const short4v* vrow = (const short4v*)(KVT + (size_t)(512 + h*64 + l)*ldkv + cb);
  const float* pp = pL + h*256;
  float ac0=0.f, ac1=0.f, ac2=0.f, ac3=0.f;
  #pragma unroll 7
  for (int c = 0; c < 49; ++c) {
    short4v v4 = vrow[c];
    ac0 += pp[c*4]   * b2f(v4.x);
    ac1 += pp[c*4+1] * b2f(v4.y);
    ac2 += pp[c*4+2] * b2f(v4.z);
    ac3 += pp[c*4+3] * b2f(v4.w);
  }
  float accv = (ac0+ac1)+(ac2+ac3);
  preb[(size_t)b*1536 + h*64 + l] = f2b(accv * inv);
}

__device__ __forceinline__ void outk_body(int tt, int b, int tid,
    float* syncL, float* wred,
    const float* actT, float* ao, float* bo_s,
    const int* li_o, const int* ri_o, const float* decay_o,
    const short* WoutB, const float* bout, float* out)
{
  int j = tid;
  float rr = expf(-clip015(decay_o[j]));
  float prod = actT[li_o[j]*64 + b] * actT[ri_o[j]*64 + b];
  float a2 = rr*ao[b*512+j] + prod; ao[b*512+j] = a2;
  float bb2 = rr*bo_s[b*512+j] + 1.f; bo_s[b*512+j] = bb2;
  syncL[j] = a2 * rsqrtf(bb2);
  __syncthreads();
  float a = bout[j];
  #pragma unroll 8
  for (int k = 0; k < 512; ++k) a += syncL[k]*b2f(WoutB[k*512+j]);
  out[((size_t)b*512 + j)*16 + tt] = a;
  int w = tid >> 6, l = tid & 63;
  float m = a;
  #pragma unroll
  for (int k = 32; k >= 1; k >>= 1) m = fmaxf(m, __shfl_xor(m, k, 64));
  if (l == 0) wred[w] = m;
  __syncthreads();
  float M = wred[0];
  #pragma unroll
  for (int k = 1; k < 8; ++k) M = fmaxf(M, wred[k]);
  float e = expf(a - M);
  float z = e, s1 = e*(a - M);
  #pragma unroll
  for (int k = 32; k >= 1; k >>= 1) { z += __shfl_xor(z, k, 64); s1 += __shfl_xor(s1, k, 64); }
  if (l == 0) { wred[8+w] = z; wred[16+w] = s1; }
  __syncthreads();
  if (tid == 0) {
    float Z = 0.f, S1 = 0.f;
    #pragma unroll
    for (int k = 0; k < 8; ++k) { Z += wred[8+k]; S1 += wred[16+k]; }
    float plp = S1 / Z - logf(Z);
    float ne = -plp * (1.f/logf(512.f));
    out[524288 + (size_t)b*32 + tt]      = ne;
    out[524288 + (size_t)b*32 + 16 + tt] = 1.f - ne;
  }
}

__device__ __forceinline__ void synglu_body(int bid, int tid, char* pool,
    const short* preb, const short* WsynP, const float* bsynF, float* u)
{
  f32x4* part = (f32x4*)pool;
  int w = tid >> 6, l = tid & 63;
  int mf = w & 3, kh = w >> 2;
  int arow = mf*16 + (l & 15);
  int kbase = kh*768 + (l >> 4)*8;
  const short* ap = preb + (size_t)arow*1536 + kbase;
  const short* bp = WsynP + (size_t)(bid*16 + (l & 15))*1536 + kbase;
  f32x4 acc = (f32x4){0.f,0.f,0.f,0.f};
  #pragma unroll 4
  for (int ks = 0; ks < 24; ++ks) {
    bf16x8 av = *(const bf16x8*)(ap + ks*32);
    bf16x8 bv = *(const bf16x8*)(bp + ks*32);
    acc = __builtin_amdgcn_mfma_f32_16x16x32_bf16(av, bv, acc, 0, 0, 0);
  }
  part[w*64 + l] = acc;
  __syncthreads();
  if (w < 4) {
    f32x4 o1 = part[w*64 + l], o2 = part[(w+4)*64 + l];
    int c = l & 15;
    int colg = bid*8 + (c & 7);
    float bias = (c < 8) ? bsynF[colg] : bsynF[1024 + colg];
    float tv[4], pv[4];
    #pragma unroll
    for (int r2 = 0; r2 < 4; ++r2) tv[r2] = o1[r2] + o2[r2] + bias;
    #pragma unroll
    for (int r2 = 0; r2 < 4; ++r2) pv[r2] = __shfl_xor(tv[r2], 8, 64);
    if (c < 8) {
      #pragma unroll
      for (int r2 = 0; r2 < 4; ++r2) {
        float uu = tv[r2] * (1.f/(1.f + expf(-pv[r2])));
        int brow = w*16 + (l >> 4)*4 + r2;
        u[brow*1024 + colg] = uu;
      }
    }
  }
}

__device__ __forceinline__ void nlmln_body(int bid, int tid, char* pool,
    const float* u, const float* gsyn, const float* bln, float* hist,
    const float* W1, const float* b1, const float* W2, const float* b2,
    float* actT, short* preb, int t)
{
  float* mstat = (float*)pool;
  float* istat = mstat + 64;
  {
    int b = tid >> 3, p = tid & 7;
    const float* up = u + b*1024 + p*128;
    float s = 0.f, s2 = 0.f;
    #pragma unroll 8
    for (int i = 0; i < 128; ++i) { float v = up[i]; s += v; s2 += v*v; }
    #pragma unroll
    for (int k = 4; k >= 1; k >>= 1) { s += __shfl_xor(s, k, 64); s2 += __shfl_xor(s2, k, 64); }
    if (p == 0) {
      float mean = s * (1.f/1024.f);
      float var  = s2 * (1.f/1024.f) - mean*mean;
      mstat[b] = mean;
      istat[b] = rsqrtf(var + 1e-5f);
    }
  }
  __syncthreads();
  int n = (bid << 3) + (tid >> 6), b = tid & 63;
  float nv = (u[b*1024 + n] - mstat[b]) * istat[b] * gsyn[n] + bln[n];
  int slot = t % MEM_;
  hist[((size_t)n*MEM_ + slot)*64 + b] = nv;
  float h[32];
  #pragma unroll
  for (int j = 0; j < 32; ++j) h[j] = b1[n*32+j];
  #pragma unroll 5
  for (int m = 0; m < MEM_; ++m) {
    int phys = (t + 1 + m) % MEM_;
    float hv = (m == MEM_-1) ? nv : hist[((size_t)n*MEM_ + phys)*64 + b];
    const float* wp = &W1[((size_t)n*MEM_ + m)*32];
    #pragma unroll
    for (int j = 0; j < 32; ++j) h[j] += hv * wp[j];
  }
  float acc = b2[n];
  #pragma unroll
  for (int j = 0; j < 32; ++j) acc += fmaxf(h[j], 0.f) * W2[n*32+j];
  actT[n*64 + b] = acc;
  preb[(size_t)b*1536 + 512 + n] = f2b(acc);
}

// ---------------------------------------------------------------------------
// Stage kernels: blocks 0-127 tick stage; blocks >=128 piggy (two op ranges).
// ---------------------------------------------------------------------------
#define PIGGY_ARGS int opA, int pfA, int nA, int opB, int pfB, \
    const float* __restrict__ xg, int t0n1, int t0n2, short* __restrict__ xTg, \
    const short* __restrict__ WkvT, \
    const float* __restrict__ bkv, short* __restrict__ kvpN, \
    float* __restrict__ muN, float* __restrict__ ivN, \
    const short* __restrict__ WkkvT, const float* __restrict__ gw, \
    const float* __restrict__ bw, short* __restrict__ KVTN, int McN
#define PIGGY_CALL do { \
    int pb = (int)blockIdx.x - 128; \
    int op_, idx_; \
    if (pb < nA) { op_ = opA; idx_ = pfA + pb; } \
    else         { op_ = opB; idx_ = pfB + (pb - nA); } \
    run_piggy(tid, op_, idx_, pool, xg, t0n1, t0n2, xTg, WkvT, bkv, \
              kvpN, muN, ivN, WkkvT, gw, bw, KVTN, McN); \
  } while (0)

__global__ __launch_bounds__(512) void stageA(
    const float* __restrict__ actT,
    float* __restrict__ aa, float* __restrict__ ba,
    const int* __restrict__ li_a, const int* __restrict__ ri_a,
    const float* __restrict__ decay_a,
    const short* __restrict__ WqqB, const float* __restrict__ bqh,
    const short* __restrict__ KVT, int ldkv, int ti,
    short* __restrict__ preb,
    float* __restrict__ ao, float* __restrict__ bo_s,
    const int* __restrict__ li_o, const int* __restrict__ ri_o,
    const float* __restrict__ decay_o,
    const short* __restrict__ WoutB, const float* __restrict__ bout,
    float* __restrict__ out, int t, PIGGY_ARGS)
{
  __shared__ __attribute__((aligned(16))) char pool[49152];
  const int bid = blockIdx.x, tid = threadIdx.x;
  if (bid < 128) {
    float* smem = (float*)pool;
    if (bid < 64)
      attn_body(bid, tid, smem, actT, aa, ba, li_a, ri_a, decay_a,
                WqqB, bqh, KVT, ldkv, ti, preb);
    else if (t > 0)
      outk_body(t-1, bid-64, tid, smem, smem+512, actT, ao, bo_s,
                li_o, ri_o, decay_o, WoutB, bout, out);
  } else {
    PIGGY_CALL;
  }
}

__global__ __launch_bounds__(512) void stageB(
    const short* __restrict__ preb, const short* __restrict__ WsynP,
    const float* __restrict__ bsynF, float* __restrict__ u, PIGGY_ARGS)
{
  __shared__ __attribute__((aligned(16))) char pool[49152];
  const int bid = blockIdx.x, tid = threadIdx.x;
  if (bid < 128) synglu_body(bid, tid, pool, preb, WsynP, bsynF, u);
  else PIGGY_CALL;
}

__global__ __launch_bounds__(512) void stageC(
    const float* __restrict__ u, const float* __restrict__ gsyn,
    const float* __restrict__ bln, float* __restrict__ hist,
    const float* __restrict__ W1, const float* __restrict__ b1,
    const float* __restrict__ W2, const float* __restrict__ b2,
    float* __restrict__ actT, short* __restrict__ preb, int t, PIGGY_ARGS)
{
  __shared__ __attribute__((aligned(16))) char pool[49152];
  const int bid = blockIdx.x, tid = threadIdx.x;
  if (bid < 128) nlmln_body(bid, tid, pool, u, gsyn, bln, hist,
                            W1, b1, W2, b2, actT, preb, t);
  else PIGGY_CALL;
}

// Final outk for t = T-1.
__global__ __launch_bounds__(512) void outk_fin(
    const float* __restrict__ actT,
    float* __restrict__ ao, float* __restrict__ bo_s,
    const int* __restrict__ li_o, const int* __restrict__ ri_o,
    const float* __restrict__ decay_o,
    const short* __restrict__ WoutB, const float* __restrict__ bout,
    float* __restrict__ out)
{
  __shared__ __attribute__((aligned(16))) float smem[544];
  outk_body(T_-1, blockIdx.x, threadIdx.x, smem, smem+512, actT, ao, bo_s,
            li_o, ri_o, decay_o, WoutB, bout, out);
}

// ---------------------------------------------------------------------------
// Standalone transpose of x over [t0, t0+tc) (fallback path).
// ---------------------------------------------------------------------------
__global__ __launch_bounds__(256) void xpose_x(const float* __restrict__ x,
                                               short* __restrict__ xT, int t0, int tc)
{
  __shared__ float tile[32][33];
  int df0 = blockIdx.x*32, s0 = blockIdx.y*32;
  int z = blockIdx.z;
  int b = z / tc, ti = z % tc;
  int tx = threadIdx.x & 31, ty = threadIdx.x >> 5;
  const float* src = x + (size_t)(b*T_ + t0 + ti) * DF_ * S_;
  #pragma unroll
  for (int i = 0; i < 4; ++i) {
    int df = df0 + ty + i*8;
    int s  = s0 + tx;
    tile[ty+i*8][tx] = (s < S_) ? src[(size_t)df*S_ + s] : 0.f;
  }
  __syncthreads();
  short* dst = xT + (size_t)((t0 + ti)*B_ + b) * S_ * DIN_;
  #pragma unroll
  for (int i = 0; i < 4; ++i) {
    int s  = s0 + ty + i*8;
    int df = df0 + tx;
    if (s < S_) dst[(size_t)s*DF_ + df] = f2b(tile[tx][ty+i*8]);
  }
}

// Standalone per-row LN stats (fallback path).
__global__ __launch_bounds__(256) void ln_stats(const short* __restrict__ in,
    float* __restrict__ mu, float* __restrict__ iv, int nrows)
{
  int w = threadIdx.x >> 6, l = threadIdx.x & 63;
  int r = blockIdx.x*4 + w;
  if (r >= nrows) return;
  bf16x8 v8 = *(const bf16x8*)&in[(size_t)r*512 + l*8];
  float s = 0.f, s2 = 0.f;
  #pragma unroll
  for (int j = 0; j < 8; ++j) { float v = b2f(v8[j]); s += v; s2 += v*v; }
  #pragma unroll
  for (int m = 1; m < 64; m <<= 1) { s += __shfl_xor(s, m, 64); s2 += __shfl_xor(s2, m, 64); }
  if (l == 0) {
    float mean = s * (1.f/512.f);
    float var  = s2 * (1.f/512.f) - mean*mean;
    mu[r] = mean;
    iv[r] = rsqrtf(var + 1e-5f);
  }
}

// ---------------------------------------------------------------------------
// prep_all: weight transposes, casts, bias folds, state init AND the
// xpose of ticks 0..3 (chunks 0-1), all in one launch.
// ---------------------------------------------------------------------------
__global__ __launch_bounds__(256) void prep_all(
    const float* __restrict__ Wkv, const float* __restrict__ Wk,
    const float* __restrict__ Wv,  const float* __restrict__ Wsyn,
    const float* __restrict__ Wq,  const float* __restrict__ Wqp,
    const float* __restrict__ Wo,  const float* __restrict__ Wout,
    const float* __restrict__ g_kv, const float* __restrict__ b_kv,
    const float* __restrict__ bk, const float* __restrict__ bv,
    const float* __restrict__ bqp, const float* __restrict__ bq,
    const float* __restrict__ bo_p, const float* __restrict__ bsyn,
    short* __restrict__ WkvT, short* __restrict__ WkkvT,
    short* __restrict__ WsynF, short* __restrict__ WsynTt,
    short* __restrict__ WqT, short* __restrict__ WqpB,
    short* __restrict__ WoB, short* __restrict__ WoutB,
    float* __restrict__ bqh, float* __restrict__ bsynF,
    float* __restrict__ gw, float* __restrict__ bw,
    float* __restrict__ aa, float* __restrict__ ba,
    float* __restrict__ ao, float* __restrict__ bo_s,
    float* __restrict__ actT, float* __restrict__ hist,
    short* __restrict__ preb,
    const float* __restrict__ init_act, const float* __restrict__ init_hist,
    const int* __restrict__ li_o, const int* __restrict__ ri_o,
    const float* __restrict__ x, short* __restrict__ xT)
{
  __shared__ float tile[32][33];
  const int blk = blockIdx.x, tid = threadIdx.x;
  auto wtr = [&](const float* in, short* out, int bx, int by,
                 int C, int ldo, int coff, const float* scale){
    int c0 = bx*32, r0 = by*32;
    int tx = tid & 31, ty = tid >> 5;
    #pragma unroll
    for (int i = 0; i < 4; ++i) {
      int r = r0+ty+i*8;
      float sc = scale ? scale[r] : 1.f;
      tile[ty+i*8][tx] = in[(size_t)r*C + c0+tx] * sc;
    }
    __syncthreads();
    #pragma unroll
    for (int i = 0; i < 4; ++i)
      out[(size_t)(c0+ty+i*8)*ldo + coff + r0+tx] = f2b(tile[tx][ty+i*8]);
  };
  auto cvt4 = [&](const float* in, short* out, int sb){
    int i = (sb*256 + tid)*4;
    #pragma unroll
    for (int j = 0; j < 4; ++j) out[i+j] = f2b(in[i+j]);
  };
  auto bfold = [&](const float* vec, const float* W, const float* base,
                   float* out, int n, int ldw){
    float a = base ? base[n] : 0.f;
    #pragma unroll 8
    for (int k = 0; k < 512; ++k) a += vec[k]*W[(size_t)k*ldw + n];
    out[n] = a;
  };

  if (blk < 256)       wtr(Wkv, WkvT, blk & 15, blk >> 4, 512, 512, 0, nullptr);
  else if (blk < 512)  { int s = blk-256;  wtr(Wk, WkkvT, s & 15, s >> 4, 512, 512, 0, g_kv); }
  else if (blk < 768)  { int s = blk-512;  wtr(Wv, WkkvT + (size_t)512*512, s & 15, s >> 4, 512, 512, 0, g_kv); }
  else if (blk < 2816) { int s = blk-768;  wtr(Wsyn + (size_t)512*2048, WsynF, s % 64, s / 64, 2048, 1536, 512, nullptr); }
  else if (blk < 3840) { int s = blk-2816; wtr(Wsyn, WsynTt, s % 64, s / 64, 2048, 512, 0, nullptr); }
  else if (blk < 4096) { int s = blk-3840; wtr(Wq, WqT, s & 15, s >> 4, 512, 512, 0, nullptr); }
  else if (blk < 4352) cvt4(Wqp,  WqpB,  blk-4096);
  else if (blk < 4608) cvt4(Wo,   WoB,   blk-4352);
  else if (blk < 4864) cvt4(Wout, WoutB, blk-4608);
  else if (blk < 4882) {
    int j = blk-4864;
    if (j < 2)        bfold(bqp,  Wq,   bq,   bqh,   j*256 + tid,      512);
    else if (j < 10)  bfold(bo_p, Wsyn, bsyn, bsynF, (j-2)*256 + tid,  2048);
    else if (j < 12)  bfold(g_kv, Wk,   nullptr, gw,       (j-10)*256 + tid, 512);
    else if (j < 14)  bfold(g_kv, Wv,   nullptr, gw + 512, (j-12)*256 + tid, 512);
    else if (j < 16)  bfold(b_kv, Wk,   bk,   bw,       (j-14)*256 + tid, 512);
    else              bfold(b_kv, Wv,   bv,   bw + 512, (j-16)*256 + tid, 512);
  } else if (blk < 11282) {
    int i = (blk-4882)*256 + tid;
    if (i < 64*512) {
      aa[i] = 0.f; ba[i] = 0.f;
      int j = i & 511;
      ao[i] = init_act[li_o[j]] * init_act[ri_o[j]];
      bo_s[i] = 1.f;
    }
    if (i < 65536) {
      int n = i >> 6, b = i & 63;
      actT[i] = init_act[n];
      preb[(size_t)b*1536 + 512 + n] = f2b(init_act[n]);
    }
    if (i < DM_*MEM_*64) {
      int nm = i >> 6;
      hist[i] = init_hist[nm];
    }
  } else {
    // xpose ticks 0..3: 1792 blocks x 16 tiles = 28672 = 16df x 7s x 256(b,t)
    int tx = tid & 31, ty = tid >> 5;
    int base = (blk - 11282) * 16;
    for (int it = 0; it < 16; ++it) {
      int gt = base + it;
      int df0 = (gt & 15) * 32;
      int r = gt >> 4;
      int s0 = (r % 7) * 32;
      int z = r / 7;              // [0,256)
      int b = z >> 2, t = z & 3;
      const float* src = x + (size_t)(b*T_ + t) * DF_ * S_;
      #pragma unroll
      for (int i = 0; i < 4; ++i) {
        int df = df0 + ty + i*8;
        int s  = s0 + tx;
        tile[ty+i*8][tx] = (s < S_) ? src[(size_t)df*S_ + s] : 0.f;
      }
      __syncthreads();
      short* dst = xT + (size_t)(t*B_ + b) * S_ * DIN_;
      #pragma unroll
      for (int i = 0; i < 4; ++i) {
        int s  = s0 + ty + i*8;
        int df = df0 + tx;
        if (s < S_) dst[(size_t)s*DF_ + df] = f2b(tile[tx][ty+i*8]);
      }
      __syncthreads();
    }
  }
}

// ---------------------------------------------------------------------------
extern "C" void kernel_launch(void* const* d_in, const int* in_sizes, int n_in,
                              void* d_out, int out_size, void* d_ws, size_t ws_size,
                              hipStream_t stream)
{
  (void)in_sizes; (void)n_in; (void)out_size;
  const float* x       = (const float*)d_in[0];
  const float* Wqp     = (const float*)d_in[1];
  const float* bqp     = (const float*)d_in[2];
  const float* Wkv     = (const float*)d_in[3];
  const float* bkv     = (const float*)d_in[4];
  const float* g_kv    = (const float*)d_in[5];
  const float* b_kv    = (const float*)d_in[6];
  const float* Wq      = (const float*)d_in[7];
  const float* bq      = (const float*)d_in[8];
  const float* Wk      = (const float*)d_in[9];
  const float* bk      = (const float*)d_in[10];
  const float* Wv      = (const float*)d_in[11];
  const float* bv      = (const float*)d_in[12];
  const float* Wo      = (const float*)d_in[13];
  const float* bo_p    = (const float*)d_in[14];
  const float* Wsyn    = (const float*)d_in[15];
  const float* bsyn    = (const float*)d_in[16];
  const float* g_syn   = (const float*)d_in[17];
  const float* b_syn   = (const float*)d_in[18];
  const float* W1      = (const float*)d_in[19];
  const float* b1      = (const float*)d_in[20];
  const float* W2      = (const float*)d_in[21];
  const float* b2      = (const float*)d_in[22];
  const float* init_act  = (const float*)d_in[23];
  const float* init_hist = (const float*)d_in[24];
  const float* decay_a = (const float*)d_in[25];
  const float* decay_o = (const float*)d_in[26];
  const float* Wout    = (const float*)d_in[27];
  const float* bout    = (const float*)d_in[28];
  const int* li_a = (const int*)d_in[29];
  const int* ri_a = (const int*)d_in[30];
  const int* li_o = (const int*)d_in[31];
  const int* ri_o = (const int*)d_in[32];

  char* ws = (char*)d_ws;
  size_t off = 0;
  auto alloc = [&](size_t bytes) { char* p = ws + off; off += (bytes + 255) & ~(size_t)255; return p; };
  short* WkvT   = (short*)alloc(512*512*2);
  short* WkkvT  = (short*)alloc(1024*512*2);
  short* WsynF  = (short*)alloc(2048*1536*2);
  short* WsynP  = (short*)alloc(2048*1536*2);
  short* WsynTt = (short*)alloc(2048*512*2);
  short* WqpB   = (short*)alloc(512*512*2);
  short* WqT    = (short*)alloc(512*512*2);
  short* WoB    = (short*)alloc(512*512*2);
  short* WqqB   = (short*)alloc(512*512*2);
  short* WoutB  = (short*)alloc(512*512*2);
  float* bqh    = (float*)alloc(512*4);
  float* bsynF  = (float*)alloc(2048*4);
  float* gw     = (float*)alloc(1024*4);
  float* bw     = (float*)alloc(1024*4);
  short* preb   = (short*)alloc(64*1536*2);
  float* u      = (float*)alloc(64*1024*4);
  float* aa     = (float*)alloc(64*512*4);
  float* ba     = (float*)alloc(64*512*4);
  float* ao     = (float*)alloc(64*512*4);
  float* bo_s   = (float*)alloc(64*512*4);
  float* actT   = (float*)alloc(1024*64*4);
  float* hist   = (float*)alloc((size_t)1024*25*64*4);
  size_t fixed_end = off;

  const size_t szXT  = (size_t)T_*MR_*512*2;     // 205.5 MB (all 16 ticks)
  const size_t szKVP = (size_t)MCC_*512*2;       //  25.7 MB per chunk
  const size_t szKVT = (size_t)MCC_*1024*2;      //  51.4 MB per chunk
  const size_t szST  = (size_t)MCC_*4;
  size_t need_full = fixed_end + szXT + 2*szKVP + 2*szKVT + 4*szST + 4096;
  bool pig_en = (ws_size >= need_full);

  short* xT = (short*)alloc(szXT);
  short* kvpB[2]; short* KVTB[2]; float* muB[2]; float* ivB[2];
  kvpB[0] = (short*)alloc(szKVP);
  KVTB[0] = (short*)alloc(szKVT);
  muB[0]  = (float*)alloc(szST);
  ivB[0]  = (float*)alloc(szST);
  if (pig_en) {
    kvpB[1] = (short*)alloc(szKVP);
    KVTB[1] = (short*)alloc(szKVT);
    muB[1]  = (float*)alloc(szST);
    ivB[1]  = (float*)alloc(szST);
  } else {
    kvpB[1] = kvpB[0]; KVTB[1] = KVTB[0]; muB[1] = muB[0]; ivB[1] = ivB[0];
  }

  const int BIG = 1 << 30;
  const float* FN = nullptr;

  prep_all<<<13074, 256, 0, stream>>>(Wkv, Wk, Wv, Wsyn, Wq, Wqp, Wo, Wout,
      g_kv, b_kv, bk, bv, bqp, bq, bo_p, bsyn,
      WkvT, WkkvT, WsynF, WsynTt, WqT, WqpB, WoB, WoutB,
      bqh, bsynF, gw, bw, aa, ba, ao, bo_s, actT, hist, preb,
      init_act, init_hist, li_o, ri_o, x, xT);
  if (!pig_en)
    xpose_x<<<dim3(16,7,B_*(T_-2*TC_)), 256, 0, stream>>>(x, xT, 2*TC_, T_-2*TC_);
  gemm_prep3<<<864, 256, 0, stream>>>(WqpB, WqT, WqqB, WsynTt, WoB, WsynF,
                                      xT, WkvT, bkv, kvpB[0]);
  permstats<<<2048 + MCC_/4, 256, 0, stream>>>(WsynF, WsynP, kvpB[0], muB[0], ivB[0]);
  gemm_k<0,2><<<dim3(8,196), 256, 0, stream>>>(WkkvT, kvpB[0], KVTB[0], nullptr, nullptr, BIG,
                                               muB[0], ivB[0], gw, bw, 1024, MCC_, 512, 512, MCC_);

  auto run_pipe = [&](int c, short* kvpP, float* muP, float* ivP, short* KVTP){
    const short* xTc = xT + (size_t)c*TC_*MR_*512;
    gemm_k<0,0><<<dim3(196,4), 256, 0, stream>>>(xTc, WkvT, kvpP, bkv, bkv, BIG,
                                                 FN, FN, FN, FN, MCC_, 512, 512, 512, 512);
    ln_stats<<<MCC_/4, 256, 0, stream>>>(kvpP, muP, ivP, MCC_);
    gemm_k<0,2><<<dim3(8,196), 256, 0, stream>>>(WkkvT, kvpP, KVTP, nullptr, nullptr, BIG,
                                                 muP, ivP, gw, bw, 1024, MCC_, 512, 512, MCC_);
  };

  // per-chunk piggy schedule over the 6 tail slots:
  // q0: op1a(196) + op4a(224); q1: op1b(196) + op4b(224);
  // q2: op2(392); q3-5: op3 (262,262,260).
  auto pigcfg = [](int q, bool p123, bool p4,
                   int& opA, int& pfA, int& nA, int& opB, int& pfB, int& nB){
    opA = 0; pfA = 0; nA = 0; opB = 0; pfB = 0; nB = 0;
    if (q == 0 || q == 1) {
      if (p123) { opA = 1; pfA = q*196; nA = 196; }
      if (p4)   { opB = 4; pfB = q*224; nB = 224; }
    } else if (q == 2) {
      if (p123) { opA = 2; pfA = 0; nA = 392; }
    } else {
      if (p123) { opA = 3; pfA = (q-3)*262; nA = (q == 5) ? 260 : 262; }
    }
  };

  for (int c = 0; c < NCH_; ++c) {
    int par = pig_en ? (c & 1) : 0;
    int nxt = pig_en ? (par ^ 1) : 0;
    if (!pig_en && c > 0) run_pipe(c, kvpB[0], muB[0], ivB[0], KVTB[0]);
    bool p123 = pig_en && (c < NCH_-1);
    bool p4   = pig_en && (c < NCH_-2);
    int t0n1 = (c < NCH_-1) ? (c+1)*TC_ : 0;
    int t0n2 = (c < NCH_-2) ? (c+2)*TC_ : 0;
    for (int ti = 0; ti < TC_; ++ti) {
      int t = c*TC_ + ti;
      int oA, fA, nA, oB, fB, nB;
      pigcfg(ti*3+0, p123, p4, oA, fA, nA, oB, fB, nB);
      stageA<<<128+nA+nB, 512, 0, stream>>>(actT, aa, ba, li_a, ri_a, decay_a,
          WqqB, bqh, KVTB[par], MCC_, ti, preb,
          ao, bo_s, li_o, ri_o, decay_o, WoutB, bout, (float*)d_out, t,
          oA, fA, nA, oB, fB, x, t0n1, t0n2, xT, WkvT, bkv,
          kvpB[nxt], muB[nxt], ivB[nxt], WkkvT, gw, bw, KVTB[nxt], MCC_);
      pigcfg(ti*3+1, p123, p4, oA, fA, nA, oB, fB, nB);
      stageB<<<128+nA+nB, 512, 0, stream>>>(preb, WsynP, bsynF, u,
          oA, fA, nA, oB, fB, x, t0n1, t0n2, xT, WkvT, bkv,
          kvpB[nxt], muB[nxt], ivB[nxt], WkkvT, gw, bw, KVTB[nxt], MCC_);
      pigcfg(ti*3+2, p123, p4, oA, fA, nA, oB, fB, nB);
      stageC<<<128+nA+nB, 512, 0, stream>>>(u, g_syn, b_syn, hist,
          W1, b1, W2, b2, actT, preb, t,
          oA, fA, nA, oB, fB, x, t0n1, t0n2, xT, WkvT, bkv,
          kvpB[nxt], muB[nxt], ivB[nxt], WkkvT, gw, bw, KVTB[nxt], MCC_);
    }
  }
  outk_fin<<<64, 512, 0, stream>>>(actT, ao, bo_s, li_o, ri_o, decay_o,
                                   WoutB, bout, (float*)d_out);
}